// Round 5
// baseline (305.520 us; speedup 1.0000x reference)
//
#include <hip/hip_runtime.h>
#include <math.h>

#define NN 5000
#define NE 160000
#define NF 16
#define CK 256
#define WSTRIDE 20   // LDS row stride in floats: 20*l mod 32 hits all 8
                     // multiples of 4 -> uniform 8 words/bank (b128 floor)

// ws layout (bytes):
// [0,      20480)  deg -> inv_sqrt (5000 f32, padded)
// [20480,  340480) h1 = x@W1      (80000 f32)
// [340480, 660480) g1 = adj@h1
// [660480, 980480) a1 = relu(g1+b1)
// [980480, 1300480) g2 = adj@a1

__global__ void k_deg(const int* __restrict__ dst, float* __restrict__ deg) {
  int t = blockIdx.x * 256 + threadIdx.x;
  if (t < NE) atomicAdd(&deg[dst[t]], 1.0f);
}

__global__ void k_inv(float* __restrict__ deg) {
  int v = blockIdx.x * 256 + threadIdx.x;
  if (v < NN) deg[v] = rsqrtf(deg[v] + 1.0f);  // +1 self loop; deg>=1 always
}

// h1 = x @ W1.  Block = 4 waves x 4 rows = 16 rows; split-k x4 (blockIdx.y).
// Lane l owns k-class (k = kc + s*64 + l):
//   x: 4 plain b32 global loads per subchunk (one per row) -- 256 B dense.
//   W: lane's W1 row read ONCE per subchunk from LDS (4x b128, stride-20
//      padding -> conflict-free), reused for all 4 rows.
//   64 FMA per subchunk per lane -> VALU-bound by design.
// Epilogue: per-row rotating butterfly (m=32..4 high-first, R4-verified) +
// full sum over m=1,2; lane (kk,jq) holds total(row jq, col kk) -> 1 atomic.
__global__ __launch_bounds__(256) void k_gemm1(const float* __restrict__ x,
                                               const float* __restrict__ w1,
                                               float* __restrict__ h1) {
  __shared__ float ws2[CK * WSTRIDE];  // 20480 B
  const int tid = threadIdx.x;
  const int lane = tid & 63;
  const int wv = tid >> 6;
  const int row0 = blockIdx.x * 16 + wv * 4;  // this wave's 4 rows
  const int kbeg = blockIdx.y * 1280;
  const int kend = (kbeg + 1280 < NN) ? kbeg + 1280 : NN;

  float acc[4][NF];
#pragma unroll
  for (int r = 0; r < 4; ++r)
#pragma unroll
    for (int j = 0; j < NF; ++j) acc[r][j] = 0.f;

  // Clamped row pointers: OOB rows read row NN-1 (harmless; atomic guarded).
  const float* __restrict__ xr0 = x + (size_t)((row0 + 0 < NN) ? row0 + 0 : NN - 1) * NN;
  const float* __restrict__ xr1 = x + (size_t)((row0 + 1 < NN) ? row0 + 1 : NN - 1) * NN;
  const float* __restrict__ xr2 = x + (size_t)((row0 + 2 < NN) ? row0 + 2 : NN - 1) * NN;
  const float* __restrict__ xr3 = x + (size_t)((row0 + 3 < NN) ? row0 + 3 : NN - 1) * NN;

  for (int kc = kbeg; kc < kend; kc += CK) {
    __syncthreads();
    {  // stage W rows [kc, kc+256) : thread t -> row kc+t (64 B coalesced)
      const int k = kc + tid;
      float4 a = make_float4(0.f, 0.f, 0.f, 0.f), b = a, c = a, d = a;
      if (k < kend) {  // zero-pad past split end: kills OOB x garbage too
        const float4* __restrict__ wr = (const float4*)(w1 + (size_t)k * NF);
        a = wr[0]; b = wr[1]; c = wr[2]; d = wr[3];
      }
      float* dp = &ws2[tid * WSTRIDE];
      *(float4*)(dp + 0) = a;  *(float4*)(dp + 4) = b;
      *(float4*)(dp + 8) = c;  *(float4*)(dp + 12) = d;
    }
    __syncthreads();
#pragma unroll
    for (int s = 0; s < 4; ++s) {
      const int kl = s * 64 + lane;
      int k = kc + kl;
      if (k > NN - 1) k = NN - 1;  // clamp addr only; W=0 past kend
      const float x0 = xr0[k];
      const float x1 = xr1[k];
      const float x2 = xr2[k];
      const float x3 = xr3[k];
      const float* __restrict__ wp = &ws2[kl * WSTRIDE];
      const float4 w0 = *(const float4*)(wp + 0);
      const float4 w1v = *(const float4*)(wp + 4);
      const float4 w2v = *(const float4*)(wp + 8);
      const float4 w3v = *(const float4*)(wp + 12);
#pragma unroll
      for (int r = 0; r < 4; ++r) {
        const float xv = (r == 0) ? x0 : (r == 1) ? x1 : (r == 2) ? x2 : x3;
        acc[r][0] = fmaf(xv, w0.x, acc[r][0]);
        acc[r][1] = fmaf(xv, w0.y, acc[r][1]);
        acc[r][2] = fmaf(xv, w0.z, acc[r][2]);
        acc[r][3] = fmaf(xv, w0.w, acc[r][3]);
        acc[r][4] = fmaf(xv, w1v.x, acc[r][4]);
        acc[r][5] = fmaf(xv, w1v.y, acc[r][5]);
        acc[r][6] = fmaf(xv, w1v.z, acc[r][6]);
        acc[r][7] = fmaf(xv, w1v.w, acc[r][7]);
        acc[r][8] = fmaf(xv, w2v.x, acc[r][8]);
        acc[r][9] = fmaf(xv, w2v.y, acc[r][9]);
        acc[r][10] = fmaf(xv, w2v.z, acc[r][10]);
        acc[r][11] = fmaf(xv, w2v.w, acc[r][11]);
        acc[r][12] = fmaf(xv, w3v.x, acc[r][12]);
        acc[r][13] = fmaf(xv, w3v.y, acc[r][13]);
        acc[r][14] = fmaf(xv, w3v.z, acc[r][14]);
        acc[r][15] = fmaf(xv, w3v.w, acc[r][15]);
      }
    }
  }

  // Epilogue: per row, rotate 16 cols over kk bits (m=32..4 high-first:
  // surviving col index == kk, R4-verified), then full-sum over jq bits.
  float tot[4];
#pragma unroll
  for (int r = 0; r < 4; ++r) {
    float v[16];
#pragma unroll
    for (int j = 0; j < 16; ++j) v[j] = acc[r][j];
    int len = 16;
#pragma unroll
    for (int m = 32; m >= 4; m >>= 1) {
      len >>= 1;
      const bool hi = (lane & m) != 0;
#pragma unroll
      for (int i = 0; i < len; ++i) {
        float keep = hi ? v[i + len] : v[i];
        float give = hi ? v[i] : v[i + len];
        v[i] = keep + __shfl_xor(give, m);
      }
    }
    float s = v[0];
    s += __shfl_xor(s, 1);
    s += __shfl_xor(s, 2);
    tot[r] = s;
  }
  const int kk = (lane >> 2) & 15;
  const int jq = lane & 3;
  float val = tot[0];
  if (jq == 1) val = tot[1];
  if (jq == 2) val = tot[2];
  if (jq == 3) val = tot[3];
  const int row = row0 + jq;
  if (row < NN) atomicAdd(&h1[row * NF + kk], val);
}

// self-loop term: g[v][j] = inv[v]^2 * h[v][j]
__global__ void k_self(const float* __restrict__ h1, const float* __restrict__ inv,
                       float* __restrict__ g1) {
  int t = blockIdx.x * 256 + threadIdx.x;
  if (t >= NN * NF) return;
  float iv = inv[t >> 4];
  g1[t] = iv * iv * h1[t];
}

// edge scatter: g[dst][j] += inv[src]*inv[dst] * h[src][j]  (16 threads/edge)
__global__ void k_edge(const int* __restrict__ src, const int* __restrict__ dst,
                       const float* __restrict__ inv, const float* __restrict__ hin,
                       float* __restrict__ gout) {
  int t = blockIdx.x * 256 + threadIdx.x;  // NE*16 = 2,560,000 = 10000*256 exact
  int e = t >> 4, j = t & 15;
  int s = src[e], d = dst[e];
  float c = inv[s] * inv[d];
  atomicAdd(&gout[d * NF + j], c * hin[s * NF + j]);
}

// a1 = relu(g1 + b1); also seed layer-2 self-loop: g2 = inv^2 * a1
__global__ void k_relu2(const float* __restrict__ g1, const float* __restrict__ b1,
                        const float* __restrict__ inv, float* __restrict__ a1,
                        float* __restrict__ g2) {
  int t = blockIdx.x * 256 + threadIdx.x;
  if (t >= NN * NF) return;
  int v = t >> 4, j = t & 15;
  float a = fmaxf(g1[t] + b1[j], 0.f);
  a1[t] = a;
  float iv = inv[v];
  g2[t] = iv * iv * a;
}

// out[row] = log_softmax(g2[row] @ W2 + b2), 4 rows per block, z staged in LDS.
__global__ __launch_bounds__(512) void k_final(const float* __restrict__ g2,
                                               const float* __restrict__ w2,
                                               const float* __restrict__ b2,
                                               float* __restrict__ out) {
  __shared__ float zs[4 * NN];   // 80000 B
  __shared__ float gsh[64];
  __shared__ float red[8 * 4];
  __shared__ float rowmax[4];
  __shared__ float rowoff[4];
  const int tid = threadIdx.x;
  const int lane = tid & 63;
  const int wv = tid >> 6;  // 8 waves
  const int row0 = blockIdx.x * 4;

  if (tid < 64) gsh[tid] = g2[row0 * NF + tid];
  __syncthreads();
  float g[4][NF];
#pragma unroll
  for (int r = 0; r < 4; ++r)
#pragma unroll
    for (int k = 0; k < NF; ++k) g[r][k] = gsh[r * NF + k];

  float mx[4] = {-1e30f, -1e30f, -1e30f, -1e30f};
  for (int jc = tid; jc < NN; jc += 512) {
    float w[NF];
#pragma unroll
    for (int k = 0; k < NF; ++k) w[k] = w2[k * NN + jc];
    const float bb = b2[jc];
#pragma unroll
    for (int r = 0; r < 4; ++r) {
      float z = bb;
#pragma unroll
      for (int k = 0; k < NF; ++k) z = fmaf(g[r][k], w[k], z);
      zs[r * NN + jc] = z;
      mx[r] = fmaxf(mx[r], z);
    }
  }
#pragma unroll
  for (int r = 0; r < 4; ++r) {
    float m = mx[r];
    for (int off = 32; off; off >>= 1) m = fmaxf(m, __shfl_xor(m, off));
    if (lane == 0) red[wv * 4 + r] = m;
  }
  __syncthreads();
  if (tid < 4) {
    float m = red[tid];
#pragma unroll
    for (int w = 1; w < 8; ++w) m = fmaxf(m, red[w * 4 + tid]);
    rowmax[tid] = m;
  }
  __syncthreads();
  const float rm0 = rowmax[0], rm1 = rowmax[1], rm2 = rowmax[2], rm3 = rowmax[3];

  float sm[4] = {0.f, 0.f, 0.f, 0.f};
  for (int jc = tid; jc < NN; jc += 512) {
    sm[0] += __expf(zs[0 * NN + jc] - rm0);
    sm[1] += __expf(zs[1 * NN + jc] - rm1);
    sm[2] += __expf(zs[2 * NN + jc] - rm2);
    sm[3] += __expf(zs[3 * NN + jc] - rm3);
  }
#pragma unroll
  for (int r = 0; r < 4; ++r) {
    float s = sm[r];
    for (int off = 32; off; off >>= 1) s += __shfl_xor(s, off);
    if (lane == 0) red[wv * 4 + r] = s;
  }
  __syncthreads();
  if (tid < 4) {
    float s = red[tid];
#pragma unroll
    for (int w = 1; w < 8; ++w) s += red[w * 4 + tid];
    rowoff[tid] = rowmax[tid] + logf(s);
  }
  __syncthreads();
  const float o0 = rowoff[0], o1 = rowoff[1], o2 = rowoff[2], o3 = rowoff[3];
  for (int jc = tid; jc < NN; jc += 512) {
    out[(size_t)(row0 + 0) * NN + jc] = zs[0 * NN + jc] - o0;
    out[(size_t)(row0 + 1) * NN + jc] = zs[1 * NN + jc] - o1;
    out[(size_t)(row0 + 2) * NN + jc] = zs[2 * NN + jc] - o2;
    out[(size_t)(row0 + 3) * NN + jc] = zs[3 * NN + jc] - o3;
  }
}

extern "C" void kernel_launch(void* const* d_in, const int* in_sizes, int n_in,
                              void* d_out, int out_size, void* d_ws, size_t ws_size,
                              hipStream_t stream) {
  const float* x  = (const float*)d_in[0];
  const int*   src = (const int*)d_in[1];
  const int*   dst = (const int*)d_in[2];
  const float* W1 = (const float*)d_in[3];
  const float* b1 = (const float*)d_in[4];
  const float* W2 = (const float*)d_in[5];
  const float* b2 = (const float*)d_in[6];
  float* out = (float*)d_out;

  char* ws = (char*)d_ws;
  float* deg = (float*)(ws);            // becomes inv_sqrt after k_inv
  float* h1  = (float*)(ws + 20480);
  float* g1  = (float*)(ws + 340480);
  float* a1  = (float*)(ws + 660480);
  float* g2  = (float*)(ws + 980480);

  // zero deg + h1 (split-k atomics accumulate into h1)
  hipMemsetAsync(d_ws, 0, 340480, stream);
  k_deg<<<(NE + 255) / 256, 256, 0, stream>>>(dst, deg);
  k_inv<<<(NN + 255) / 256, 256, 0, stream>>>(deg);
  k_gemm1<<<dim3(313, 4), 256, 0, stream>>>(x, W1, h1);
  k_self<<<(NN * NF + 255) / 256, 256, 0, stream>>>(h1, deg, g1);
  k_edge<<<(NE * NF) / 256, 256, 0, stream>>>(src, dst, deg, h1, g1);
  k_relu2<<<(NN * NF + 255) / 256, 256, 0, stream>>>(g1, b1, deg, a1, g2);
  k_edge<<<(NE * NF) / 256, 256, 0, stream>>>(src, dst, deg, a1, g2);
  k_final<<<NN / 4, 512, 0, stream>>>(g2, W2, b2, out);
}

// Round 6
// 268.419 us; speedup vs baseline: 1.1382x; 1.1382x over previous
//
#include <hip/hip_runtime.h>
#include <math.h>

#define NN 5000
#define NE 160000
#define NF 16
#define KS 640      // k per split (grid.y = 8): 7x640 + 520
#define WTS 648     // LDS k-stride (bf16 units): 648*2B=1296B=324 words,
                    // 324%32=4 -> n..n+8 share a bank (2-way = free, m136)

typedef __attribute__((ext_vector_type(8))) short bf16x8;  // 4 VGPRs
typedef __attribute__((ext_vector_type(4))) float f32x4;   // MFMA acc

// ws layout (bytes):
// [0,      20480)  deg -> inv_sqrt (5000 f32, padded)
// [20480,  340480) h1 = x@W1      (80000 f32)
// [340480, 660480) g1 = adj@h1
// [660480, 980480) a1 = relu(g1+b1)
// [980480, 1300480) g2 = adj@a1

__device__ __forceinline__ short f2bf(float f) {  // RNE f32->bf16
  union { float f; unsigned u; } v; v.f = f;
  unsigned r = v.u + 0x7FFFu + ((v.u >> 16) & 1u);
  return (short)(r >> 16);
}

__global__ void k_deg(const int* __restrict__ dst, float* __restrict__ deg) {
  int t = blockIdx.x * 256 + threadIdx.x;
  if (t < NE) atomicAdd(&deg[dst[t]], 1.0f);
}

__global__ void k_inv(float* __restrict__ deg) {
  int v = blockIdx.x * 256 + threadIdx.x;
  if (v < NN) deg[v] = rsqrtf(deg[v] + 1.0f);  // +1 self loop; deg>=1 always
}

// h1 = x @ W1 via mfma_f32_16x16x32_bf16 (fp32 accumulate), split-k x8.
// Wave = one 16-row x 16-col tile over k-range [kb, kb+klen).
// A frag: lane holds x[m0+(lane&15)][k + quad*8 + j], j=0..7 -- loaded as
//   2x float4 from global (64B segments x16 rows per instr), cvt to bf16.
// B frag: W1 chunk staged once per block into LDS transposed wt[n][k] bf16
//   (stride WTS=648 -> 2-way bank aliasing only); 1x ds_read_b128 per step.
// D: row = quad*4+reg, col = lane&15 (m89-verified) -> 4 atomicAdd/lane.
__global__ __launch_bounds__(256) void k_gemm1(const float* __restrict__ x,
                                               const float* __restrict__ w1,
                                               float* __restrict__ h1) {
  __shared__ short wt[NF * WTS];  // 20736 B
  const int tid = threadIdx.x;
  const int lane = tid & 63;
  const int wv = tid >> 6;
  const int kb = blockIdx.y * KS;
  const int klen = (NN - kb < KS) ? (NN - kb) : KS;   // 640 or 520
  const int nsteps = (klen + 31) >> 5;                // 20 or 17

  // Stage W1[kb..kb+KS) -> wt[n][kk], zero-padded past NN.
  for (int kk = tid; kk < KS; kk += 256) {
    const int kg = kb + kk;
    if (kg < NN) {
      const float4* __restrict__ wr = (const float4*)(w1 + (size_t)kg * NF);
      const float4 a = wr[0], b = wr[1], c = wr[2], d = wr[3];
      wt[0 * WTS + kk] = f2bf(a.x);  wt[1 * WTS + kk] = f2bf(a.y);
      wt[2 * WTS + kk] = f2bf(a.z);  wt[3 * WTS + kk] = f2bf(a.w);
      wt[4 * WTS + kk] = f2bf(b.x);  wt[5 * WTS + kk] = f2bf(b.y);
      wt[6 * WTS + kk] = f2bf(b.z);  wt[7 * WTS + kk] = f2bf(b.w);
      wt[8 * WTS + kk] = f2bf(c.x);  wt[9 * WTS + kk] = f2bf(c.y);
      wt[10 * WTS + kk] = f2bf(c.z); wt[11 * WTS + kk] = f2bf(c.w);
      wt[12 * WTS + kk] = f2bf(d.x); wt[13 * WTS + kk] = f2bf(d.y);
      wt[14 * WTS + kk] = f2bf(d.z); wt[15 * WTS + kk] = f2bf(d.w);
    } else {
#pragma unroll
      for (int n = 0; n < NF; ++n) wt[n * WTS + kk] = 0;
    }
  }
  __syncthreads();

  const int tile = blockIdx.x * 4 + wv;   // 0..315 (313 real)
  const int m0 = tile * 16;
  int arow = m0 + (lane & 15);
  if (arow > NN - 1) arow = NN - 1;       // clamp addr; write guarded below
  const float* __restrict__ xr = x + (size_t)arow * NN + kb;
  const int quad = lane >> 4;
  const short* __restrict__ bp = &wt[(lane & 15) * WTS + quad * 8];

  f32x4 acc = {0.f, 0.f, 0.f, 0.f};
  for (int s = 0; s < nsteps; ++s) {
    const int k0 = s * 32 + quad * 8;     // offset within split (8-aligned)
    bf16x8 a;
    if (kb + k0 < NN) {                   // whole 8-chunk valid (NN%8==0)
      const float4 xa = *(const float4*)(xr + k0);
      const float4 xb = *(const float4*)(xr + k0 + 4);
      a[0] = f2bf(xa.x); a[1] = f2bf(xa.y); a[2] = f2bf(xa.z); a[3] = f2bf(xa.w);
      a[4] = f2bf(xb.x); a[5] = f2bf(xb.y); a[6] = f2bf(xb.z); a[7] = f2bf(xb.w);
    } else {
#pragma unroll
      for (int j = 0; j < 8; ++j) a[j] = 0;
    }
    const bf16x8 b = *(const bf16x8*)(bp + s * 32);  // 16B-aligned ds_read_b128
    acc = __builtin_amdgcn_mfma_f32_16x16x32_bf16(a, b, acc, 0, 0, 0);
  }

  const int col = lane & 15;
#pragma unroll
  for (int r = 0; r < 4; ++r) {
    const int orow = m0 + quad * 4 + r;
    if (orow < NN) atomicAdd(&h1[orow * NF + col], acc[r]);
  }
}

// self-loop term: g[v][j] = inv[v]^2 * h[v][j]
__global__ void k_self(const float* __restrict__ h1, const float* __restrict__ inv,
                       float* __restrict__ g1) {
  int t = blockIdx.x * 256 + threadIdx.x;
  if (t >= NN * NF) return;
  float iv = inv[t >> 4];
  g1[t] = iv * iv * h1[t];
}

// edge scatter: g[dst][j] += inv[src]*inv[dst] * h[src][j]  (16 threads/edge)
__global__ void k_edge(const int* __restrict__ src, const int* __restrict__ dst,
                       const float* __restrict__ inv, const float* __restrict__ hin,
                       float* __restrict__ gout) {
  int t = blockIdx.x * 256 + threadIdx.x;  // NE*16 = 2,560,000 = 10000*256 exact
  int e = t >> 4, j = t & 15;
  int s = src[e], d = dst[e];
  float c = inv[s] * inv[d];
  atomicAdd(&gout[d * NF + j], c * hin[s * NF + j]);
}

// a1 = relu(g1 + b1); also seed layer-2 self-loop: g2 = inv^2 * a1
__global__ void k_relu2(const float* __restrict__ g1, const float* __restrict__ b1,
                        const float* __restrict__ inv, float* __restrict__ a1,
                        float* __restrict__ g2) {
  int t = blockIdx.x * 256 + threadIdx.x;
  if (t >= NN * NF) return;
  int v = t >> 4, j = t & 15;
  float a = fmaxf(g1[t] + b1[j], 0.f);
  a1[t] = a;
  float iv = inv[v];
  g2[t] = iv * iv * a;
}

// out[row] = log_softmax(g2[row] @ W2 + b2), 4 rows per block, z staged in LDS.
__global__ __launch_bounds__(512) void k_final(const float* __restrict__ g2,
                                               const float* __restrict__ w2,
                                               const float* __restrict__ b2,
                                               float* __restrict__ out) {
  __shared__ float zs[4 * NN];   // 80000 B
  __shared__ float gsh[64];
  __shared__ float red[8 * 4];
  __shared__ float rowmax[4];
  __shared__ float rowoff[4];
  const int tid = threadIdx.x;
  const int lane = tid & 63;
  const int wv = tid >> 6;  // 8 waves
  const int row0 = blockIdx.x * 4;

  if (tid < 64) gsh[tid] = g2[row0 * NF + tid];
  __syncthreads();
  float g[4][NF];
#pragma unroll
  for (int r = 0; r < 4; ++r)
#pragma unroll
    for (int k = 0; k < NF; ++k) g[r][k] = gsh[r * NF + k];

  float mx[4] = {-1e30f, -1e30f, -1e30f, -1e30f};
  for (int jc = tid; jc < NN; jc += 512) {
    float w[NF];
#pragma unroll
    for (int k = 0; k < NF; ++k) w[k] = w2[k * NN + jc];
    const float bb = b2[jc];
#pragma unroll
    for (int r = 0; r < 4; ++r) {
      float z = bb;
#pragma unroll
      for (int k = 0; k < NF; ++k) z = fmaf(g[r][k], w[k], z);
      zs[r * NN + jc] = z;
      mx[r] = fmaxf(mx[r], z);
    }
  }
#pragma unroll
  for (int r = 0; r < 4; ++r) {
    float m = mx[r];
    for (int off = 32; off; off >>= 1) m = fmaxf(m, __shfl_xor(m, off));
    if (lane == 0) red[wv * 4 + r] = m;
  }
  __syncthreads();
  if (tid < 4) {
    float m = red[tid];
#pragma unroll
    for (int w = 1; w < 8; ++w) m = fmaxf(m, red[w * 4 + tid]);
    rowmax[tid] = m;
  }
  __syncthreads();
  const float rm0 = rowmax[0], rm1 = rowmax[1], rm2 = rowmax[2], rm3 = rowmax[3];

  float sm[4] = {0.f, 0.f, 0.f, 0.f};
  for (int jc = tid; jc < NN; jc += 512) {
    sm[0] += __expf(zs[0 * NN + jc] - rm0);
    sm[1] += __expf(zs[1 * NN + jc] - rm1);
    sm[2] += __expf(zs[2 * NN + jc] - rm2);
    sm[3] += __expf(zs[3 * NN + jc] - rm3);
  }
#pragma unroll
  for (int r = 0; r < 4; ++r) {
    float s = sm[r];
    for (int off = 32; off; off >>= 1) s += __shfl_xor(s, off);
    if (lane == 0) red[wv * 4 + r] = s;
  }
  __syncthreads();
  if (tid < 4) {
    float s = red[tid];
#pragma unroll
    for (int w = 1; w < 8; ++w) s += red[w * 4 + tid];
    rowoff[tid] = rowmax[tid] + logf(s);
  }
  __syncthreads();
  const float o0 = rowoff[0], o1 = rowoff[1], o2 = rowoff[2], o3 = rowoff[3];
  for (int jc = tid; jc < NN; jc += 512) {
    out[(size_t)(row0 + 0) * NN + jc] = zs[0 * NN + jc] - o0;
    out[(size_t)(row0 + 1) * NN + jc] = zs[1 * NN + jc] - o1;
    out[(size_t)(row0 + 2) * NN + jc] = zs[2 * NN + jc] - o2;
    out[(size_t)(row0 + 3) * NN + jc] = zs[3 * NN + jc] - o3;
  }
}

extern "C" void kernel_launch(void* const* d_in, const int* in_sizes, int n_in,
                              void* d_out, int out_size, void* d_ws, size_t ws_size,
                              hipStream_t stream) {
  const float* x  = (const float*)d_in[0];
  const int*   src = (const int*)d_in[1];
  const int*   dst = (const int*)d_in[2];
  const float* W1 = (const float*)d_in[3];
  const float* b1 = (const float*)d_in[4];
  const float* W2 = (const float*)d_in[5];
  const float* b2 = (const float*)d_in[6];
  float* out = (float*)d_out;

  char* ws = (char*)d_ws;
  float* deg = (float*)(ws);            // becomes inv_sqrt after k_inv
  float* h1  = (float*)(ws + 20480);
  float* g1  = (float*)(ws + 340480);
  float* a1  = (float*)(ws + 660480);
  float* g2  = (float*)(ws + 980480);

  // zero deg + h1 (split-k atomics accumulate into h1)
  hipMemsetAsync(d_ws, 0, 340480, stream);
  k_deg<<<(NE + 255) / 256, 256, 0, stream>>>(dst, deg);
  k_inv<<<(NN + 255) / 256, 256, 0, stream>>>(deg);
  k_gemm1<<<dim3(79, 8), 256, 0, stream>>>(x, W1, h1);
  k_self<<<(NN * NF + 255) / 256, 256, 0, stream>>>(h1, deg, g1);
  k_edge<<<(NE * NF) / 256, 256, 0, stream>>>(src, dst, deg, h1, g1);
  k_relu2<<<(NN * NF + 255) / 256, 256, 0, stream>>>(g1, b1, deg, a1, g2);
  k_edge<<<(NE * NF) / 256, 256, 0, stream>>>(src, dst, deg, a1, g2);
  k_final<<<NN / 4, 512, 0, stream>>>(g2, W2, b2, out);
}